// Round 3
// baseline (70.969 us; speedup 1.0000x reference)
//
#include <hip/hip_runtime.h>

// x[b,i,p,j,q,l,r] = sum_k y[b,k,i,j,l] * W[k,0,p,q,r]
// y: (4,64,64,8,8) f32 ; W: (64,1,16,4,4) f32 ; out: (4,1,1024,32,32) f32
// Output float4 index (over r) within fixed (b,i): idx4 = p*256 + j*32 + q*8 + l.
//
// Grid: 1024 blocks = (b,i) x p-quarter, 256 thr, LDS 32 KB -> 4 blocks/CU,
// 16 waves/CU. Direct 64B-contiguous-per-lane stores (no LDS round-trip):
// the 4 store instrs fully cover each 128B line, L2 write-combines.

__device__ __forceinline__ void fma4(float4& a, float s, const float4& w) {
    a.x += s * w.x; a.y += s * w.y; a.z += s * w.z; a.w += s * w.w;
}

__global__ __launch_bounds__(256, 4) void backproj_kernel(
    const float* __restrict__ y, const float* __restrict__ W,
    float* __restrict__ out)
{
    // ws: [k][v] float4 over r, v = pq within quarter (16). 16 KB.
    __shared__ float4 ws[64 * 16];
    // ys: [k][c] float4 over jl (c = jl/4). 16 KB.
    __shared__ float4 ys[64 * 16];

    const int tid = threadIdx.x;
    const int blk = blockIdx.x;          // blk = (b*64+i)*4 + qtr
    const int bi  = blk >> 2;
    const int qtr = blk & 3;             // p in [qtr*4, qtr*4+4)
    const int b   = bi >> 6;
    const int i   = bi & 63;

    // ---- stage W quarter: 1024 float4s, coalesced (256B runs) ----
    const float4* Wg4 = (const float4*)W;   // flat f = k*64 + pq
    #pragma unroll
    for (int t = 0; t < 4; ++t) {
        int f = tid + t * 256;              // f = k*16 + v
        ws[f] = Wg4[(f >> 4) * 64 + qtr * 16 + (f & 15)];
    }
    // ---- stage y slice: 1024 float4s (256B runs per k) ----
    const float4* yg4 = (const float4*)y;   // flat f4 = (b*64+k)*1024 + i*16 + c
    #pragma unroll
    for (int t = 0; t < 4; ++t) {
        int f = tid + t * 256;              // f = k*16 + c
        ys[f] = yg4[(b * 64 + (f >> 4)) * 1024 + i * 16 + (f & 15)];
    }
    __syncthreads();

    // ---- compute: thread = (u, g); u -> 1 pq column, g -> 4 jl rows ----
    const int u = tid & 15;              // pq within quarter
    const int g = tid >> 4;              // jl group: jl = g*4 + m

    float4 acc[4];
    #pragma unroll
    for (int m = 0; m < 4; ++m) acc[m] = float4{0.f, 0.f, 0.f, 0.f};

    #pragma unroll 8
    for (int k = 0; k < 64; ++k) {
        float4 w  = ws[k * 16 + u];      // 16 distinct float4, 2-way bank alias: free
        float4 yv = ys[k * 16 + g];      // 4 distinct, 16-way broadcast
        fma4(acc[0], yv.x, w);
        fma4(acc[1], yv.y, w);
        fma4(acc[2], yv.z, w);
        fma4(acc[3], yv.w, w);
    }

    // ---- direct store: each thread owns 4 consecutive float4 (64 B) ----
    // acc[m] -> jl = g*4+m -> j = g>>1, l = (g&1)*4 + m
    const int pl = u >> 2, q = u & 3;
    const int base = pl * 256 + (g >> 1) * 32 + q * 8 + (g & 1) * 4;
    float4* og4 = (float4*)out + (size_t)bi * 4096 + qtr * 1024 + base;
    #pragma unroll
    for (int m = 0; m < 4; ++m) og4[m] = acc[m];
}

extern "C" void kernel_launch(void* const* d_in, const int* in_sizes, int n_in,
                              void* d_out, int out_size, void* d_ws, size_t ws_size,
                              hipStream_t stream) {
    const float* y = (const float*)d_in[0];   // 4*64*64*8*8 = 1048576
    const float* W = (const float*)d_in[1];   // 64*1*16*4*4 = 16384
    float* out = (float*)d_out;               // 4*1*1024*32*32 = 4194304
    backproj_kernel<<<dim3(1024), dim3(256), 0, stream>>>(y, W, out);
}